// Round 7
// baseline (340.877 us; speedup 1.0000x reference)
//
#include <hip/hip_runtime.h>
#include <hip/hip_bf16.h>

typedef _Float16 half8 __attribute__((ext_vector_type(8)));
typedef float f32x4 __attribute__((ext_vector_type(4)));

// ---------------- helpers ----------------
static __device__ __forceinline__ float bf2f_lo(unsigned u) {
    return __uint_as_float(u << 16);
}
static __device__ __forceinline__ float bf2f_hi(unsigned u) {
    return __uint_as_float(u & 0xffff0000u);
}
static __device__ __forceinline__ unsigned f2bf_rne_bits(float f) {
    unsigned u = __float_as_uint(f);
    return u + 0x7fffu + ((u >> 16) & 1u);
}
static __device__ __forceinline__ unsigned pack_bf2(float a, float b) {
    return (f2bf_rne_bits(a) >> 16) | (f2bf_rne_bits(b) & 0xffff0000u);
}
static __device__ __forceinline__ float pfun(float e) {
    e = fmaxf(e, 0.2f * e);   // leaky_relu(0.2)
    return __expf(e);         // |e| small -> no max-subtraction needed
}
static __device__ __forceinline__ unsigned pack_h2(float a, float b) {
    union { _Float16 f[2]; unsigned u; } pk;
    pk.f[0] = (_Float16)a; pk.f[1] = (_Float16)b;
    return pk.u;
}

// ================= CSR build: two-level bucket sort =================
#define CHUNK 4096

// count + (last block) scan fused via ticket. bucketCount/ticket pre-zeroed
// by hipMemsetAsync.
__global__ void kb_count(const int* __restrict__ dst, int* bucketCount, int* ticket,
                         int* bucketBase, int* bucketCursor, int* row_ptr,
                         int E, int T, int NBK, int N, int nblocks) {
    __shared__ int cnt[256];
    __shared__ int sm[256];
    __shared__ int isLast;
    const int tid = threadIdx.x;
    const int beg = blockIdx.x * CHUNK;
    const int end = min(beg + CHUNK, T);
    cnt[tid] = 0;
    __syncthreads();
    for (int i = beg + tid; i < end; i += 256) {
        int d = (i < E) ? dst[i] : (i - E);
        atomicAdd(&cnt[d >> 8], 1);
    }
    __syncthreads();
    if (tid < NBK && cnt[tid] > 0) atomicAdd(&bucketCount[tid], cnt[tid]);
    __threadfence();
    __syncthreads();
    if (tid == 0) isLast = (atomicAdd(ticket, 1) == nblocks - 1);
    __syncthreads();
    if (!isLast) return;
    // coherent read of all buckets (device-scope atomic load), then scan
    int v = (tid < NBK) ? atomicAdd(&bucketCount[tid], 0) : 0;
    sm[tid] = v;
    __syncthreads();
    for (int off = 1; off < 256; off <<= 1) {
        int t = (tid >= off) ? sm[tid - off] : 0;
        __syncthreads();
        sm[tid] += t;
        __syncthreads();
    }
    if (tid < NBK) {
        int ex = sm[tid] - v;
        bucketBase[tid] = ex;
        bucketCursor[tid] = ex;
    }
    if (tid == 0) {
        bucketBase[NBK] = T;
        row_ptr[N] = T;
    }
}

__global__ void kb_place(const int* __restrict__ src, const int* __restrict__ dst,
                         int* bucketCursor, unsigned* __restrict__ barr,
                         int E, int T, int NBK) {
    __shared__ int cnt[256];
    __shared__ int wb[256];
    const int tid = threadIdx.x;
    const int beg = blockIdx.x * CHUNK;
    const int end = min(beg + CHUNK, T);
    cnt[tid] = 0;
    __syncthreads();
    for (int i = beg + tid; i < end; i += 256) {
        int d = (i < E) ? dst[i] : (i - E);
        atomicAdd(&cnt[d >> 8], 1);
    }
    __syncthreads();
    if (tid < NBK) {
        int c = cnt[tid];
        wb[tid] = (c > 0) ? atomicAdd(&bucketCursor[tid], c) : 0;
    }
    __syncthreads();
    cnt[tid] = 0;
    __syncthreads();
    for (int i = beg + tid; i < end; i += 256) {
        int s, d;
        if (i < E) { s = src[i]; d = dst[i]; }
        else       { s = i - E;  d = s; }
        int g = d >> 8;
        unsigned pk = (unsigned)s | ((unsigned)(d & 255) << 16);
        int r = atomicAdd(&cnt[g], 1);
        barr[wb[g] + r] = pk;
    }
}

__global__ void kb_csr(const unsigned* __restrict__ barr, const int* __restrict__ bucketBase,
                       int* __restrict__ row_ptr, int* __restrict__ col, int N) {
    __shared__ int cnt[256];
    __shared__ int sm[256];
    __shared__ int cur[256];
    const int tid = threadIdx.x;
    const int b = blockIdx.x;
    const int beg = bucketBase[b];
    const int end = bucketBase[b + 1];
    cnt[tid] = 0;
    __syncthreads();
    for (int i = beg + tid; i < end; i += 256)
        atomicAdd(&cnt[barr[i] >> 16], 1);
    __syncthreads();
    int v = cnt[tid];
    sm[tid] = v;
    __syncthreads();
    for (int off = 1; off < 256; off <<= 1) {
        int t = (tid >= off) ? sm[tid - off] : 0;
        __syncthreads();
        sm[tid] += t;
        __syncthreads();
    }
    int ex = sm[tid] - v;
    int n = b * 256 + tid;
    if (n < N) row_ptr[n] = beg + ex;
    cur[tid] = beg + ex;
    __syncthreads();
    for (int i = beg + tid; i < end; i += 256) {
        unsigned p = barr[i];
        int pos = atomicAdd(&cur[p >> 16], 1);
        col[pos] = (int)(p & 0xFFFFu);
    }
}

// ---------------- MFMA GEMM: h = A @ W + alpha epilogue ----------------
// A-op = W^T (LDS), B-op = A rows. HALF_IN: A already fp16 (layer 2, written
// by k_aggr) -> no cvt, 4x fewer A bytes. Wt stride 140 halves (bank spread).
template <bool HALF_IN>
__launch_bounds__(256)
__global__ void k_gemm(const void* __restrict__ Ain, const float* __restrict__ W,
                       const float* __restrict__ a_src, const float* __restrict__ a_dst,
                       unsigned* __restrict__ Hout,
                       float* __restrict__ asrc_o, float* __restrict__ adst_o,
                       int nrows, int ntiles) {
    __shared__ _Float16 Wt[128 * 140];
    const int tid = threadIdx.x;
    for (int idx = tid; idx < 128 * 128 / 4; idx += 256) {
        int k = idx >> 5;
        int c4 = (idx & 31) * 4;
        float4 v = *(const float4*)&W[(size_t)k * 128 + c4];
        Wt[(c4 + 0) * 140 + k] = (_Float16)v.x;
        Wt[(c4 + 1) * 140 + k] = (_Float16)v.y;
        Wt[(c4 + 2) * 140 + k] = (_Float16)v.z;
        Wt[(c4 + 3) * 140 + k] = (_Float16)v.w;
    }
    __syncthreads();
    const int lane = tid & 63;
    const int m = lane & 15, quad = lane >> 4;

    half8 wf[4][8];
#pragma unroll
    for (int ks = 0; ks < 4; ++ks)
#pragma unroll
        for (int ct = 0; ct < 8; ++ct)
            wf[ks][ct] = *(half8*)&Wt[(ct * 16 + m) * 140 + ks * 32 + quad * 8];

    const int wv = (blockIdx.x * 256 + tid) >> 6;
    const int nwaves = gridDim.x * 4;
    for (int t = wv; t < ntiles; t += nwaves) {
        const int row = t * 16 + m;
        const int rc = min(row, nrows - 1);
        f32x4 acc[8];
#pragma unroll
        for (int ct = 0; ct < 8; ++ct) acc[ct] = (f32x4){0.f, 0.f, 0.f, 0.f};
#pragma unroll
        for (int ks = 0; ks < 4; ++ks) {
            half8 af;
            if (HALF_IN) {
                const _Float16* ap = (const _Float16*)Ain + (size_t)rc * 128;
                af = *(const half8*)&ap[ks * 32 + quad * 8];
            } else {
                const float* ap = (const float*)Ain + (size_t)rc * 128;
                float4 x0 = *(const float4*)&ap[ks * 32 + quad * 8];
                float4 x1 = *(const float4*)&ap[ks * 32 + quad * 8 + 4];
                af[0] = (_Float16)x0.x; af[1] = (_Float16)x0.y;
                af[2] = (_Float16)x0.z; af[3] = (_Float16)x0.w;
                af[4] = (_Float16)x1.x; af[5] = (_Float16)x1.y;
                af[6] = (_Float16)x1.z; af[7] = (_Float16)x1.w;
            }
#pragma unroll
            for (int ct = 0; ct < 8; ++ct)
                acc[ct] = __builtin_amdgcn_mfma_f32_16x16x32_f16(wf[ks][ct], af, acc[ct], 0, 0, 0);
        }
        if (row < nrows) {
#pragma unroll
            for (int ct = 0; ct < 8; ++ct) {
                uint2 o;
                o.x = pack_bf2(acc[ct][0], acc[ct][1]);
                o.y = pack_bf2(acc[ct][2], acc[ct][3]);
                *(uint2*)&Hout[(size_t)row * 64 + ct * 8 + quad * 2] = o;
            }
        }
        float ps[4] = {0.f, 0.f, 0.f, 0.f}, pd[4] = {0.f, 0.f, 0.f, 0.f};
#pragma unroll
        for (int ct = 0; ct < 8; ++ct) {
            int hh = ct >> 1;
#pragma unroll
            for (int r = 0; r < 4; ++r) {
                int c = ct * 16 + quad * 4 + r;
                ps[hh] += acc[ct][r] * a_src[c];
                pd[hh] += acc[ct][r] * a_dst[c];
            }
        }
#pragma unroll
        for (int hh = 0; hh < 4; ++hh) {
            ps[hh] += __shfl_xor(ps[hh], 16); ps[hh] += __shfl_xor(ps[hh], 32);
            pd[hh] += __shfl_xor(pd[hh], 16); pd[hh] += __shfl_xor(pd[hh], 32);
        }
        if (row < nrows) {
            asrc_o[(size_t)row * 4 + quad] = ps[quad];
            adst_o[(size_t)row * 4 + quad] = pd[quad];
        }
    }
}

// ---------------- fused softmax-aggregate + bias + ELU ----------------
// 2-batch software pipeline: next batch's 16 h-gathers issued BEFORE current
// batch's FMAs -> up to ~34 outstanding VMEM/wave (MLP experiment vs L3-BW).
// out_h != null (layer 1): write fp16 (feeds HALF_IN gemm, numerically
// identical to prior in-gemm cvt). out_f != null (layer 2): fp32 d_out.
#define BAT 16
__launch_bounds__(256)
__global__ void k_aggr(const unsigned* __restrict__ h,
                       const float* __restrict__ asrc, const float* __restrict__ adst,
                       const float* __restrict__ bias,
                       const int* __restrict__ row_ptr, const int* __restrict__ col,
                       float* __restrict__ out_f, unsigned* __restrict__ out_h, int N) {
    const int lane = threadIdx.x & 63;
    const int d = blockIdx.x * 4 + (threadIdx.x >> 6);
    if (d >= N) return;
    const int eb  = lane >> 2;
    const int hp  = lane & 3;
    const int hdc = lane >> 4;
    const float adv = adst[(size_t)d * 4 + hp];
    const int beg = row_ptr[d];
    const int end = row_ptr[d + 1];

    float ac0 = 0.f, ac1 = 0.f, sp = 0.f;

    int cv = 0;
    { int idx = beg + eb; if (idx < end) cv = col[idx]; }
    unsigned ucur[BAT];
#pragma unroll
    for (int k = 0; k < BAT; ++k) {
        int sk = __builtin_amdgcn_readlane(cv, 4 * k);
        ucur[k] = h[(size_t)(unsigned)sk * 64 + lane];
    }

    for (int j = beg; j < end; j += BAT) {
        int cvn = 0;
        { int idx = j + BAT + eb; if (idx < end) cvn = col[idx]; }

        float a = asrc[(size_t)(unsigned)cv * 4 + hp];
        float p = (j + eb < end) ? pfun(a + adv) : 0.f;
        sp += p;

        unsigned unext[BAT];
        if (j + BAT < end) {   // wave-uniform
#pragma unroll
            for (int k = 0; k < BAT; ++k) {
                int sk = __builtin_amdgcn_readlane(cvn, 4 * k);
                unext[k] = h[(size_t)(unsigned)sk * 64 + lane];
            }
        }
#pragma unroll
        for (int k = 0; k < BAT; ++k) {
            float pk = __shfl(p, 4 * k + hdc);
            ac0 += pk * bf2f_lo(ucur[k]);
            ac1 += pk * bf2f_hi(ucur[k]);
        }
#pragma unroll
        for (int k = 0; k < BAT; ++k) ucur[k] = unext[k];
        cv = cvn;
    }

    sp += __shfl_xor(sp, 4);
    sp += __shfl_xor(sp, 8);
    sp += __shfl_xor(sp, 16);
    sp += __shfl_xor(sp, 32);
    float spv = __shfl(sp, hdc);
    float inv = 1.f / spv;

    int c = 2 * lane;
    float v0 = ac0 * inv + bias[c];
    float v1 = ac1 * inv + bias[c + 1];
    v0 = (v0 > 0.f) ? v0 : (__expf(v0) - 1.f);
    v1 = (v1 > 0.f) ? v1 : (__expf(v1) - 1.f);
    if (out_h) {
        out_h[(size_t)d * 64 + lane] = pack_h2(v0, v1);
    } else {
        *(float2*)&out_f[(size_t)d * 128 + c] = make_float2(v0, v1);
    }
}

// ---------------- launch ----------------
extern "C" void kernel_launch(void* const* d_in, const int* in_sizes, int n_in,
                              void* d_out, int out_size, void* d_ws, size_t ws_size,
                              hipStream_t stream) {
    const float* x      = (const float*)d_in[0];
    const int*   ei     = (const int*)d_in[1];
    const float* W1     = (const float*)d_in[2];
    const float* a_src1 = (const float*)d_in[3];
    const float* a_dst1 = (const float*)d_in[4];
    const float* b1     = (const float*)d_in[5];
    const float* W2     = (const float*)d_in[6];
    const float* a_src2 = (const float*)d_in[7];
    const float* a_dst2 = (const float*)d_in[8];
    const float* b2     = (const float*)d_in[9];

    const int N = in_sizes[0] / 128;
    const int E = in_sizes[1] / 2;
    const int T = E + N;
    const int NBK = (N + 255) / 256;      // needs N <= 65536
    const int* src = ei;
    const int* dst = ei + E;

    char* w = (char*)d_ws;
    auto alloc = [&](size_t bytes) -> char* {
        char* p = w;
        w += (bytes + 255) & ~(size_t)255;
        return p;
    };
    unsigned* h_bf    = (unsigned*)alloc((size_t)N * 64 * 4);   // bf16 h
    unsigned* o1h     = (unsigned*)alloc((size_t)N * 64 * 4);   // fp16 layer-1 out
    float*    asrc    = (float*)alloc((size_t)N * 4 * 4);
    float*    adst    = (float*)alloc((size_t)N * 4 * 4);
    int*      row_ptr = (int*)alloc((size_t)(N + 1) * 4);
    int*      col     = (int*)alloc((size_t)T * 4);
    unsigned* barr    = (unsigned*)alloc((size_t)T * 4);
    int*      bCount  = (int*)alloc((size_t)(NBK + 1) * 4);     // +1 = ticket
    int*      bBase   = (int*)alloc((size_t)(NBK + 1) * 4);
    int*      bCursor = (int*)alloc((size_t)NBK * 4);
    int*      ticket  = bCount + NBK;
    (void)ws_size; (void)n_in; (void)out_size;

    const int PB = (T + CHUNK - 1) / CHUNK;

    hipMemsetAsync(bCount, 0, (size_t)(NBK + 1) * 4, stream);
    hipLaunchKernelGGL(kb_count, dim3(PB), dim3(256), 0, stream,
                       dst, bCount, ticket, bBase, bCursor, row_ptr, E, T, NBK, N, PB);
    hipLaunchKernelGGL(kb_place, dim3(PB), dim3(256), 0, stream, src, dst, bCursor, barr, E, T, NBK);
    hipLaunchKernelGGL(kb_csr, dim3(NBK), dim3(256), 0, stream, barr, bBase, row_ptr, col, N);

    const int ntiles = (N + 15) / 16;
    const int GB = 512;
    const int AB = (N + 3) / 4;

    hipLaunchKernelGGL((k_gemm<false>), dim3(GB), dim3(256), 0, stream,
                       (const void*)x, W1, a_src1, a_dst1, h_bf, asrc, adst, N, ntiles);
    hipLaunchKernelGGL(k_aggr, dim3(AB), dim3(256), 0, stream,
                       h_bf, asrc, adst, b1, row_ptr, col, (float*)nullptr, o1h, N);
    hipLaunchKernelGGL((k_gemm<true>), dim3(GB), dim3(256), 0, stream,
                       (const void*)o1h, W2, a_src2, a_dst2, h_bf, asrc, adst, N, ntiles);
    hipLaunchKernelGGL(k_aggr, dim3(AB), dim3(256), 0, stream,
                       h_bf, asrc, adst, b2, row_ptr, col, (float*)d_out, (unsigned*)nullptr, N);
}